// Round 5
// 1560.683 us; speedup vs baseline: 1.1531x; 1.1531x over previous
//
#include <hip/hip_runtime.h>
#include <hip/hip_bf16.h>

// LSTM_Sequence_Prediction — MI355X, round 12.
// R8-R11 (XCD-local L2 exchange) all failed at infra level with no counters;
// root cause not localizable blind. R12 retreats to the VERIFIED R7 kernel
// set (1799.66 us, passed) and takes the one zero-protocol-risk win:
// the decoder recurrence is INDEPENDENT of the encoder (it starts from zeros
// per the reference's call-site bug), so its persistent kernel is fused into
// the encoder launch as 48 extra blocks (blockIdx >= 96 -> verbatim dec
// path). Its ~hundreds of us of latency-chain wall-time hide entirely under
// the encoder's 1381 us. Combined static LDS 61.7KB < 64KB; 144 blocks <=
// 256 CUs so co-residency is unconditional. All paths byte-identical to R7.

constexpr int NB = 64;    // batch
constexpr int NH = 768;   // hidden
constexpr int NF = 256;   // features
constexpr int NS = 256;   // seq len
constexpr int NT = 32;    // target len
constexpr int ENC_BLOCKS = 96;   // 48 unit-tiles x 2 batch halves
constexpr int ENC_GROUP  = 48;   // blocks per batch-half barrier group
constexpr int DEC_BLOCKS = 48;   // 768 units / 16

typedef short bf16x8 __attribute__((ext_vector_type(8)));
typedef float f32x4 __attribute__((ext_vector_type(4)));

__device__ __forceinline__ float sigm(float x) { return 1.f / (1.f + expf(-x)); }

// LLC-direct (coherent) accesses: sc0 sc1 bypass L1 and the non-coherent XCD L2.
__device__ __forceinline__ int4 ld_i4_cohere(const int4* p) {
    int4 v;
    asm volatile("global_load_dwordx4 %0, %1, off sc0 sc1" : "=v"(v) : "v"(p));
    return v;   // NOT ready until vm_drain()!
}
__device__ __forceinline__ int ld_i1_cohere_sync(const int* p) {
    int v;
    asm volatile("global_load_dword %0, %1, off sc0 sc1\n\ts_waitcnt vmcnt(0)"
                 : "=v"(v) : "v"(p) : "memory");
    return v;
}
__device__ __forceinline__ void st_i1_cohere(int* p, int v) {
    asm volatile("global_store_dword %0, %1, off sc0 sc1" :: "v"(p), "v"(v) : "memory");
}
__device__ __forceinline__ void vm_drain() {
    asm volatile("s_waitcnt vmcnt(0)" ::: "memory");
}

// Group barrier: arrival = coherent slot store (after data drained); wait =
// wave-0 lane i watches slot i (nb <= 64: exactly one slot per lane).
__device__ __forceinline__ void arrive(int* slots, int idx, int phase) {
    if (threadIdx.x == 0) st_i1_cohere(slots + idx * 16, phase);
}
__device__ __forceinline__ void wait_all(int* slots, int phase, int nb) {
    if (threadIdx.x < nb) {
        const int* p = slots + threadIdx.x * 16;
        while (ld_i1_cohere_sync(p) < phase) __builtin_amdgcn_s_sleep(1);
    }
    __syncthreads();
}

// Fused fp32 -> bf16 conversion for all four regions (dst contiguous in ws).
__global__ __launch_bounds__(256) void cvt_all(
    const float* __restrict__ s0,   //       4,194,304 el (x)
    const float* __restrict__ s1,   //         786,432 el (e_Wih0)
    const float* __restrict__ s2,   //       2,359,296 el (e_Whh0)
    const float* __restrict__ s3,   //       4,718,592 el (e_Wih[0..1])
    __hip_bfloat16* __restrict__ d) // 12,058,624 el total
{
    const int i = (blockIdx.x * 256 + threadIdx.x) * 4;
    const float* s; int off;
    if (i < 4194304)      { s = s0; off = 0; }
    else if (i < 4980736) { s = s1; off = 4194304; }
    else if (i < 7340032) { s = s2; off = 4980736; }
    else                  { s = s3; off = 7340032; }
    const float4 v = *(const float4*)(s + (i - off));
    d[i]     = __float2bfloat16(v.x);
    d[i + 1] = __float2bfloat16(v.y);
    d[i + 2] = __float2bfloat16(v.z);
    d[i + 3] = __float2bfloat16(v.w);
}

// Fused persistent kernel.
//   blocks 0..95   : encoder layer 0 (verbatim R7 enc_persist). Block = 4
//                    waves; wave g = gate g for a 16-unit tile over 32 batch
//                    rows; h crosses blocks as packed bf16 pairs, LLC-direct;
//                    barrier per-batch-half (48 blocks).
//   blocks 96..143 : decoder (verbatim R7 dec_persist), fully independent of
//                    the encoder (initial hidden is zeros), so it runs in the
//                    encoder's shadow for free.
__global__ __launch_bounds__(256, 1) void enc_dec_persist(
    const __hip_bfloat16* __restrict__ xb,    // NS x NB x NF bf16 (cached)
    const __hip_bfloat16* __restrict__ Wx,    // 4H x NF bf16 (cached)
    const __hip_bfloat16* __restrict__ Wh,    // 4H x NH bf16 (cached)
    const float* __restrict__ bih, const float* __restrict__ bhh,
    int* __restrict__ h0buf,                  // NB x 384 int (zero-inited)
    int* __restrict__ h1buf,                  // NB x 384 int
    float* __restrict__ enc0,                 // NB x NH fp32 (final h out)
    int* slots,                               // enc: 2 groups x 48 x 16 ints
    const float* __restrict__ dW,             // decoder layer-2 Wih (fp32)
    const float* __restrict__ dbih, const float* __restrict__ dbhh,
    float* __restrict__ hd0, float* __restrict__ hd1,
    float* __restrict__ hall, int* dslots)    // dec: 48 x 16 ints
{
    // combined static LDS: 49,664 + 8,704 + 256 + 3,072 = 61,696 B (< 64 KiB)
    __shared__ int   hst[32 * 388];           // enc: staged h (+4-int pad/row)
    __shared__ float gbuf[4][32][17];         // enc: gate staging
    __shared__ float lbias[64];               // enc: fused bias
    __shared__ float hstD[768];               // dec: staged h

    const int tid = threadIdx.x;

    if (blockIdx.x >= ENC_BLOCKS) {
        // ================= decoder path (verbatim R7) =================
        const int dbid = blockIdx.x - ENC_BLOCKS;
        const int ul = tid >> 4;
        const int j  = tid & 15;
        const int u  = dbid * 16 + ul;
        const float* Wi = dW + (size_t)u * NH;
        const float* Wg = dW + (size_t)(2 * NH + u) * NH;
        const float* Wo = dW + (size_t)(3 * NH + u) * NH;
        const float bi = dbih[u]          + dbhh[u];
        const float bg = dbih[2 * NH + u] + dbhh[2 * NH + u];
        const float bo = dbih[3 * NH + u] + dbhh[3 * NH + u];

        for (int t = 0; t < NT; ++t) {
            const float* hin = (t & 1) ? hd1 : hd0;
            float* hout      = (t & 1) ? hd0 : hd1;
            if (t > 0) wait_all(dslots, t, DEC_BLOCKS);
            if (tid < 192) {
                int4 v = ld_i4_cohere((const int4*)hin + tid);
                vm_drain();
                ((int4*)hstD)[tid] = v;
            }
            __syncthreads();
            float ai = 0.f, ag = 0.f, ao = 0.f;
            for (int k = j; k < NH; k += 16) {
                const float hv = hstD[k];
                ai += hv * Wi[k];
                ag += hv * Wg[k];
                ao += hv * Wo[k];
            }
            #pragma unroll
            for (int off = 8; off > 0; off >>= 1) {
                ai += __shfl_xor(ai, off, 16);
                ag += __shfl_xor(ag, off, 16);
                ao += __shfl_xor(ao, off, 16);
            }
            if (j == 0) {
                const float cn = sigm(ai + bi) * tanhf(ag + bg);
                const float hn = sigm(ao + bo) * tanhf(cn);
                hall[(size_t)t * NH + u] = hn;         // plain (read post-dispatch)
                if (t < NT - 1)
                    st_i1_cohere((int*)(hout + u), __float_as_int(hn));
            }
            if (t < NT - 1) {
                vm_drain();
                __syncthreads();
                arrive(dslots, dbid, t + 1);
            }
        }
        return;
    }

    // ================= encoder path (verbatim R7) =================
    const int bu = blockIdx.x % (NH / 16);    // unit tile (48)
    const int bm = blockIdx.x / (NH / 16);    // batch half (2)
    int* gslots = slots + bm * ENC_GROUP * 16;
    const int u0 = bu * 16;
    const int g = tid >> 6;                   // wave index == gate index
    const int lane = tid & 63;
    const int r = lane & 15;
    const int q = lane >> 4;
    const int row0 = bm * 32 + r;
    const int row1 = row0 + 16;

    // weight B-fragments (ordinary cached loads; L1/L2 stay warm — no
    // invalidates anywhere in this kernel)
    const size_t wrow = (size_t)(g * NH + u0 + r);
    bf16x8 wx[8], wh[24];
    #pragma unroll
    for (int c = 0; c < 8; ++c)
        wx[c] = *(const bf16x8*)(Wx + wrow * NF + c * 32 + q * 8);
    #pragma unroll
    for (int c = 0; c < 24; ++c)
        wh[c] = *(const bf16x8*)(Wh + wrow * NH + c * 32 + q * 8);

    if (tid < 64)
        lbias[tid] = bih[(tid >> 4) * NH + u0 + (tid & 15)]
                   + bhh[(tid >> 4) * NH + u0 + (tid & 15)];
    __syncthreads();

    float cst[2] = {0.f, 0.f};                // cell state, 2 cells/thread

    for (int t = 0; t < NS; ++t) {
        const int* hcur = (t & 1) ? h1buf : h0buf;
        int* hnext      = (t & 1) ? h0buf : h1buf;
        const __hip_bfloat16* xt = xb + (size_t)t * NB * NF;

        // ---- x-part (independent of h_t): overlaps the barrier wait ----
        f32x4 acc0 = {0.f, 0.f, 0.f, 0.f};
        f32x4 acc1 = {0.f, 0.f, 0.f, 0.f};
        #pragma unroll
        for (int c = 0; c < 8; ++c) {
            const bf16x8 a0 = *(const bf16x8*)(xt + (size_t)row0 * NF + c * 32 + q * 8);
            const bf16x8 a1 = *(const bf16x8*)(xt + (size_t)row1 * NF + c * 32 + q * 8);
            acc0 = __builtin_amdgcn_mfma_f32_16x16x32_bf16(a0, wx[c], acc0, 0, 0, 0);
            acc1 = __builtin_amdgcn_mfma_f32_16x16x32_bf16(a1, wx[c], acc1, 0, 0, 0);
        }

        if (t > 0) wait_all(gslots, t, ENC_GROUP);

        // ---- stage this half's h_t (48 KB) into LDS, LLC-direct ----
        {
            const int4* src = (const int4*)hcur + bm * 3072;
            int4 v[12];
            #pragma unroll
            for (int i = 0; i < 12; ++i) v[i] = ld_i4_cohere(src + i * 256 + tid);
            vm_drain();
            #pragma unroll
            for (int i = 0; i < 12; ++i) {
                const int k = i * 256 + tid;          // int4 index
                const int rw = k / 96, cl = k % 96;   // row, int4-col
                *(int4*)(hst + rw * 388 + cl * 4) = v[i];
            }
        }
        __syncthreads();

        // ---- h-part MFMAs from LDS ----
        #pragma unroll
        for (int c = 0; c < 24; ++c) {
            const bf16x8 a0 = *(const bf16x8*)((const short*)hst + r * 776 + c * 32 + q * 8);
            const bf16x8 a1 = *(const bf16x8*)((const short*)hst + (r + 16) * 776 + c * 32 + q * 8);
            acc0 = __builtin_amdgcn_mfma_f32_16x16x32_bf16(a0, wh[c], acc0, 0, 0, 0);
            acc1 = __builtin_amdgcn_mfma_f32_16x16x32_bf16(a1, wh[c], acc1, 0, 0, 0);
        }

        // C/D layout: col = lane&15 (unit), row = (lane>>4)*4 + reg
        #pragma unroll
        for (int i = 0; i < 4; ++i) {
            gbuf[g][q * 4 + i][r]      = acc0[i];
            gbuf[g][16 + q * 4 + i][r] = acc1[i];
        }
        __syncthreads();

        // ---- fused cell epilogue: 2 adjacent units per thread ----
        {
            const int rowl = tid >> 3, pair = tid & 7;
            const int ua = pair * 2;
            float h2[2];
            #pragma unroll
            for (int e = 0; e < 2; ++e) {
                const int ul = ua + e;
                const float pi = gbuf[0][rowl][ul] + lbias[ul];
                const float pf = gbuf[1][rowl][ul] + lbias[16 + ul];
                const float pg = gbuf[2][rowl][ul] + lbias[32 + ul];
                const float po = gbuf[3][rowl][ul] + lbias[48 + ul];
                const float cn = sigm(pf) * cst[e] + sigm(pi) * tanhf(pg);
                h2[e] = sigm(po) * tanhf(cn);
                cst[e] = cn;
            }
            const int b = bm * 32 + rowl;
            if (t == NS - 1) {
                enc0[(size_t)b * NH + u0 + ua]     = h2[0];
                enc0[(size_t)b * NH + u0 + ua + 1] = h2[1];
                __hip_bfloat16* hf = (__hip_bfloat16*)hnext;
                hf[(size_t)b * NH + u0 + ua]     = __float2bfloat16(h2[0]);
                hf[(size_t)b * NH + u0 + ua + 1] = __float2bfloat16(h2[1]);
            } else {
                union { __hip_bfloat16 b16; unsigned short s; } c0, c1;
                c0.b16 = __float2bfloat16(h2[0]);
                c1.b16 = __float2bfloat16(h2[1]);
                const int pv = (int)c0.s | ((int)c1.s << 16);
                st_i1_cohere(hnext + (size_t)b * 384 + (u0 >> 1) + pair, pv);
            }
        }
        if (t < NS - 1) {
            vm_drain();          // h stores acked at LLC
            __syncthreads();     // all threads' stores acked
            arrive(gslots, bu, t + 1);
        }
    }
}

// One-shot LSTM step (encoder layers 1..2): gates = xin@Wx^T + b; c_prev = 0.
template<int KX, int KH>
__global__ __launch_bounds__(256) void lstm_step(
    const __hip_bfloat16* __restrict__ xin,
    const __hip_bfloat16* __restrict__ hin,
    const __hip_bfloat16* __restrict__ Wx,
    const __hip_bfloat16* __restrict__ Wh,
    const float* __restrict__ bih, const float* __restrict__ bhh,
    const float* __restrict__ c_in,
    __hip_bfloat16* __restrict__ h_bf,
    float* __restrict__ h_f32,
    float* __restrict__ c_out)
{
    constexpr int K = KX + KH;
    constexpr int NCH = K / 32;
    const int bu = blockIdx.x % (NH / 16);
    const int bm = blockIdx.x / (NH / 16);
    const int u0 = bu * 16;
    const int tid = threadIdx.x;
    const int g = tid >> 6;
    const int lane = tid & 63;
    const int r = lane & 15;
    const int q = lane >> 4;

    f32x4 acc0 = {0.f, 0.f, 0.f, 0.f};
    f32x4 acc1 = {0.f, 0.f, 0.f, 0.f};
    const int row0 = bm * 32 + r;
    const int row1 = row0 + 16;
    const long wr = (long)(g * NH + u0 + r);

    #pragma unroll
    for (int c = 0; c < NCH; ++c) {
        const int k0 = c * 32;
        bf16x8 a0, a1, bfrag;
        if (k0 < KX) {
            const int kk = k0 + q * 8;
            a0 = *(const bf16x8*)(xin + (long)row0 * KX + kk);
            a1 = *(const bf16x8*)(xin + (long)row1 * KX + kk);
            bfrag = *(const bf16x8*)(Wx + wr * KX + kk);
        } else {
            const int kk = (k0 - KX) + q * 8;
            a0 = *(const bf16x8*)(hin + (long)row0 * KH + kk);
            a1 = *(const bf16x8*)(hin + (long)row1 * KH + kk);
            bfrag = *(const bf16x8*)(Wh + wr * KH + kk);
        }
        acc0 = __builtin_amdgcn_mfma_f32_16x16x32_bf16(a0, bfrag, acc0, 0, 0, 0);
        acc1 = __builtin_amdgcn_mfma_f32_16x16x32_bf16(a1, bfrag, acc1, 0, 0, 0);
    }

    __shared__ float gbuf[4][32][17];
    #pragma unroll
    for (int i = 0; i < 4; ++i) {
        gbuf[g][q * 4 + i][r]      = acc0[i];
        gbuf[g][16 + q * 4 + i][r] = acc1[i];
    }
    __syncthreads();

    #pragma unroll
    for (int i = 0; i < 2; ++i) {
        const int idx = tid + i * 256;
        const int bl = idx >> 4;
        const int u  = idx & 15;
        const int gu = u0 + u;
        const int b  = bm * 32 + bl;
        const float pi = gbuf[0][bl][u] + bih[gu]          + bhh[gu];
        const float pf = gbuf[1][bl][u] + bih[NH + gu]     + bhh[NH + gu];
        const float pg = gbuf[2][bl][u] + bih[2 * NH + gu] + bhh[2 * NH + gu];
        const float po = gbuf[3][bl][u] + bih[3 * NH + gu] + bhh[3 * NH + gu];
        const float cp = c_in ? c_in[(long)b * NH + gu] : 0.f;
        const float cn = sigm(pf) * cp + sigm(pi) * tanhf(pg);
        const float hn = sigm(po) * tanhf(cn);
        if (c_out) c_out[(long)b * NH + gu] = cn;
        if (h_f32) h_f32[(long)b * NH + gu] = hn;
        h_bf[(long)b * NH + gu] = __float2bfloat16(hn);
    }
}

// Head: out[t,b,f] = hdec_all[t]@lin_W^T + lin_b, broadcast over batch.
__global__ __launch_bounds__(256) void head_kernel(
    const float* __restrict__ hall,
    const float* __restrict__ lw,
    const float* __restrict__ lb,
    float* __restrict__ out)
{
    const int t = blockIdx.x;
    const int f = threadIdx.x;
    const float* h = hall + (size_t)t * NH;
    const float4* wrow = (const float4*)(lw + (size_t)f * NH);
    float acc = 0.f;
    for (int k4 = 0; k4 < NH / 4; ++k4) {
        const float4 w = wrow[k4];
        acc += h[k4 * 4]     * w.x;
        acc += h[k4 * 4 + 1] * w.y;
        acc += h[k4 * 4 + 2] * w.z;
        acc += h[k4 * 4 + 3] * w.w;
    }
    acc += lb[f];
    float* o = out + (size_t)t * NB * NF + f;
    for (int b = 0; b < NB; ++b) o[(size_t)b * NF] = acc;
}

extern "C" void kernel_launch(void* const* d_in, const int* in_sizes, int n_in,
                              void* d_out, int out_size, void* d_ws, size_t ws_size,
                              hipStream_t stream) {
    (void)in_sizes; (void)n_in; (void)out_size; (void)ws_size;
    const float* x     = (const float*)d_in[0];
    const float* eWih0 = (const float*)d_in[1];
    const float* eWhh0 = (const float*)d_in[2];
    const float* ebih0 = (const float*)d_in[3];
    const float* ebhh0 = (const float*)d_in[4];
    const float* eWih  = (const float*)d_in[5];
    // d_in[6] = e_Whh : provably unused
    const float* ebih  = (const float*)d_in[7];
    const float* ebhh  = (const float*)d_in[8];
    const float* dWih  = (const float*)d_in[9];
    // d_in[10] = d_Whh : provably unused
    const float* dbih  = (const float*)d_in[11];
    const float* dbhh  = (const float*)d_in[12];
    const float* linW  = (const float*)d_in[13];
    const float* linb  = (const float*)d_in[14];
    float* out = (float*)d_out;

    // ---- workspace layout (bytes) ----
    char* ws = (char*)d_ws;
    __hip_bfloat16* xb   = (__hip_bfloat16*)(ws);              // 8,388,608 B
    __hip_bfloat16* W0x  = (__hip_bfloat16*)(ws +  8388608);   // 1,572,864 B
    __hip_bfloat16* W0h  = (__hip_bfloat16*)(ws +  9961472);   // 4,718,592 B
    __hip_bfloat16* eW12 = (__hip_bfloat16*)(ws + 14680064);   // 9,437,184 B
    int* hbi0 = (int*)(ws + 24117248);                         // 98,304 B (NB x 384)
    int* hbi1 = (int*)(ws + 24215552);                         // 98,304 B
    float* hd0  = (float*)(ws + 24313856);                     // 3,072 B
    float* hd1  = (float*)(ws + 24316928);                     // 3,072 B
    float* hall = (float*)(ws + 24320000);                     // 98,304 B
    int* bar    = (int*)(ws + 24418304);                       // 16,384 B
    int* enc_slots = bar;                  // 2 groups x 48 x 64 B = 6144 B
    int* dec_slots = bar + 2048;           // +8192 B: 48 x 64 B

    // zero initial states + barrier slots (ws poisoned 0xAA each call)
    (void)hipMemsetAsync(hbi0, 0, (size_t)NB * NH * 2, stream);
    (void)hipMemsetAsync(hd0, 0, (size_t)NH * 4, stream);
    (void)hipMemsetAsync(bar, 0, 16384, stream);

    // one fused fp32 -> bf16 conversion kernel (dst contiguous at ws+0)
    cvt_all<<<12058624 / 1024, 256, 0, stream>>>(x, eWih0, eWhh0, eWih,
                                                 (__hip_bfloat16*)ws);

    float* enc = out + (size_t)NT * NB * NF;                   // encoder_hidden slab

    // fused encoder layer 0 + decoder: 96 enc blocks + 48 dec blocks, one
    // persistent launch; the independent decoder hides under the encoder.
    const float* W2 = dWih + (size_t)2 * 4 * NH * NH;
    enc_dec_persist<<<ENC_BLOCKS + DEC_BLOCKS, 256, 0, stream>>>(
        xb, W0x, W0h, ebih0, ebhh0, hbi0, hbi1, enc, enc_slots,
        W2, dbih + 2 * 4 * NH, dbhh + 2 * 4 * NH, hd0, hd1, hall, dec_slots);

    // encoder layers 1..2 (final enc h lands in hbi0 viewed as bf16)
    __hip_bfloat16* hb0 = (__hip_bfloat16*)hbi0;
    __hip_bfloat16* hb1 = (__hip_bfloat16*)hbi1;
    lstm_step<NH, 0><<<96, 256, 0, stream>>>(
        hb0, nullptr, eW12, nullptr, ebih, ebhh,
        nullptr, hb1, enc + NB * NH, nullptr);
    lstm_step<NH, 0><<<96, 256, 0, stream>>>(
        hb1, nullptr, eW12 + (size_t)4 * NH * NH, nullptr,
        ebih + 4 * NH, ebhh + 4 * NH,
        nullptr, hb0, enc + 2 * (size_t)NB * NH, nullptr);

    // head + batch broadcast
    head_kernel<<<NT, NF, 0, stream>>>(hall, linW, linb, out);
}